// Round 2
// baseline (48.554 us; speedup 1.0000x reference)
//
#include <hip/hip_runtime.h>
#include <math.h>

#define NUM_RADIAL 8
#define EMB_DIM    64
#define N_ELEM     83
#define TILE       64   // edges per block (256 threads, 4 threads/edge phase 1)

typedef float f4 __attribute__((ext_vector_type(4)));
typedef float f2 __attribute__((ext_vector_type(2)));

// ---------------------------------------------------------------------------
// Kernel 1: t_table[z][k] = emb_table[z] . dense_w[:,k] + dense_b[k]
// ---------------------------------------------------------------------------
__global__ void srb_precompute_t(const float* __restrict__ emb,
                                 const float* __restrict__ dw,
                                 const float* __restrict__ db,
                                 float* __restrict__ t_table) {
    int idx = blockIdx.x * blockDim.x + threadIdx.x;
    if (idx >= N_ELEM * NUM_RADIAL) return;
    int z = idx >> 3;
    int k = idx & 7;
    float acc = db[k];
    const float* e = emb + z * EMB_DIM;
    #pragma unroll 8
    for (int j = 0; j < EMB_DIM; ++j)
        acc += e[j] * dw[j * NUM_RADIAL + k];
    t_table[idx] = acc;
}

// ---------------------------------------------------------------------------
// Kernel 2: main edge kernel, 64 edges / 256-thread block.
// Phase 1 (4 threads per edge): Y[16] (sub 0) and G[4][8] (2 k-channels per
//   sub-thread) into LDS.  G[l][k] = t[k]*rb[k]*w[l][k]*sigmoid(t*rb*w[0][k])
// Phase 2: 2048 float4 per block, consecutive lanes -> consecutive float4
//   (fully coalesced nontemporal stores). out[e][lm][k] = Y[lm]*G[deg(lm)][k]
// LDS 13.6 KB -> 8 blocks/CU -> 32 waves/CU (wave cap).
// ---------------------------------------------------------------------------
__global__ __launch_bounds__(256) void srb_main(
    const float* __restrict__ disp,
    const int*   __restrict__ Zj,
    const float* __restrict__ tw,       // tensor_w, 4 x 8
    const float* __restrict__ t_table,  // 83 x 8
    float*       __restrict__ out,
    int n_edges)
{
    __shared__ float Yl[TILE * 17];   // stride 17 (odd): conflict-free b32
    __shared__ float Gl[TILE * 36];   // stride 36: rows 16B-aligned -> b128

    const int tid = threadIdx.x;
    const int el  = tid >> 2;         // local edge 0..63
    const int sub = tid & 3;          // 2 radial channels per sub-thread
    const int e   = blockIdx.x * TILE + el;

    if (e < n_edges) {
        const float dx = disp[3 * e + 0];
        const float dy = disp[3 * e + 1];
        const float dz = disp[3 * e + 2];
        const float r2 = dx * dx + dy * dy + dz * dz;
        const float r  = sqrtf(r2);
        const float rinv = (r > 0.0f) ? (1.0f / r) : 0.0f;
        const float x = dx * rinv, y = dy * rinv, z = dz * rinv;
        const float x2 = x * x, y2 = y * y, z2 = z * z;

        const float PI = 3.14159265358979323846f;
        const float cut = (r < 5.0f) ? (0.5f * (__cosf(PI * r * 0.2f) + 1.0f))
                                     : 0.0f;
        const float pib = PI * r * 0.2f;   // pi*r/CUTOFF

        if (sub == 0) {
            const float s3   = 1.7320508075688772f;   // sqrt(3)
            const float s15  = 3.8729833462074170f;   // sqrt(15)
            const float s5_8 = 0.7905694150420949f;   // sqrt(5/8)
            const float s3_8 = 0.6123724356957945f;   // sqrt(3/8)
            float* Yp = &Yl[el * 17];
            Yp[0]  = 1.0f;
            Yp[1]  = x;
            Yp[2]  = y;
            Yp[3]  = z;
            Yp[4]  = s3 * x * y;
            Yp[5]  = s3 * y * z;
            Yp[6]  = 0.5f * (3.0f * z2 - 1.0f);
            Yp[7]  = s3 * x * z;
            Yp[8]  = 0.5f * s3 * (x2 - y2);
            Yp[9]  = s5_8 * y * (3.0f * x2 - y2);
            Yp[10] = s15 * x * y * z;
            Yp[11] = s3_8 * y * (5.0f * z2 - 1.0f);
            Yp[12] = 0.5f * z * (5.0f * z2 - 3.0f);
            Yp[13] = s3_8 * x * (5.0f * z2 - 1.0f);
            Yp[14] = 0.5f * s15 * z * (x2 - y2);
            Yp[15] = s5_8 * x * (x2 - 3.0f * y2);
        }

        // this sub-thread's 2 radial channels: k = 2*sub, 2*sub+1
        const int zidx = Zj[e];
        const f2 t2 = *reinterpret_cast<const f2*>(t_table + zidx * NUM_RADIAL + 2 * sub);

        float cg[2];
        #pragma unroll
        for (int kk = 0; kk < 2; ++kk) {
            const int   k  = 2 * sub + kk;
            const float px = pib * (float)(k + 1);
            const float s  = (px != 0.0f) ? (__sinf(px) / px) : 1.0f;  // sinc
            const float rb = s * cut;
            const float c  = ((kk == 0) ? t2.x : t2.y) * rb;
            const float y0 = c * tw[k];                  // w[0][k]
            const float gate = 1.0f / (1.0f + __expf(-y0));
            cg[kk] = c * gate;
        }
        float* Gp = &Gl[el * 36 + 2 * sub];
        #pragma unroll
        for (int l = 0; l < 4; ++l) {
            f2 v;
            v.x = cg[0] * tw[l * NUM_RADIAL + 2 * sub + 0];
            v.y = cg[1] * tw[l * NUM_RADIAL + 2 * sub + 1];
            *reinterpret_cast<f2*>(&Gp[l * NUM_RADIAL]) = v;
        }
    }

    __syncthreads();

    // Phase 2: coalesced nontemporal output stream
    const int totalF4 = n_edges * 32;
    const int baseF4  = blockIdx.x * (TILE * 32);
    f4* out4 = reinterpret_cast<f4*>(out);
    #pragma unroll
    for (int it = 0; it < 8; ++it) {
        const int lf = it * 256 + tid;                // [0, 2048)
        const int f  = baseF4 + lf;
        if (f < totalF4) {
            const int el2 = lf >> 5;                  // local edge
            const int j   = lf & 31;                  // float4 within edge
            const int lm  = j >> 1;
            const int k0  = (j & 1) * 4;
            const int l   = (lm > 0) + (lm > 3) + (lm > 8);
            const float yv = Yl[el2 * 17 + lm];
            const f4 g = *reinterpret_cast<const f4*>(&Gl[el2 * 36 + l * 8 + k0]);
            const f4 o = yv * g;                      // splat-mul
            __builtin_nontemporal_store(o, &out4[f]);
        }
    }
}

extern "C" void kernel_launch(void* const* d_in, const int* in_sizes, int n_in,
                              void* d_out, int out_size, void* d_ws, size_t ws_size,
                              hipStream_t stream) {
    const float* disp = (const float*)d_in[0];
    const int*   Zj   = (const int*)  d_in[1];
    const float* emb  = (const float*)d_in[2];
    const float* dw   = (const float*)d_in[3];
    const float* db   = (const float*)d_in[4];
    const float* tw   = (const float*)d_in[5];
    float* t_table = (float*)d_ws;                    // 83*8 floats = 2656 B
    float* out     = (float*)d_out;

    const int n = in_sizes[1];                        // N_EDGES

    hipLaunchKernelGGL(srb_precompute_t, dim3(3), dim3(256), 0, stream,
                       emb, dw, db, t_table);

    const int nblocks = (n + TILE - 1) / TILE;
    hipLaunchKernelGGL(srb_main, dim3(nblocks), dim3(256), 0, stream,
                       disp, Zj, tw, t_table, out, n);
}

// Round 4
// 45.013 us; speedup vs baseline: 1.0787x; 1.0787x over previous
//
#include <hip/hip_runtime.h>
#include <math.h>

#define NUM_RADIAL 8
#define EMB_DIM    64
#define N_ELEM     83
#define TILE       256   // edges per block == threads per block

typedef float f4 __attribute__((ext_vector_type(4)));
typedef float f2 __attribute__((ext_vector_type(2)));

// ---------------------------------------------------------------------------
// Kernel 1: t_table[z][k] = emb_table[z] . dense_w[:,k] + dense_b[k]
// ---------------------------------------------------------------------------
__global__ void srb_precompute_t(const float* __restrict__ emb,
                                 const float* __restrict__ dw,
                                 const float* __restrict__ db,
                                 float* __restrict__ t_table) {
    int idx = blockIdx.x * blockDim.x + threadIdx.x;
    if (idx >= N_ELEM * NUM_RADIAL) return;
    int z = idx >> 3;
    int k = idx & 7;
    float acc = db[k];
    const float* e = emb + z * EMB_DIM;
    #pragma unroll 8
    for (int j = 0; j < EMB_DIM; ++j)
        acc += e[j] * dw[j * NUM_RADIAL + k];
    t_table[idx] = acc;
}

// ---------------------------------------------------------------------------
// Kernel 2: main edge kernel. 256 edges / 256-thread block, 1 thread = 1 edge
// in phase 1 (no divergence).
// LDS holds per edge only Y[16] (stride 17) and cg[8] (stride 8):
//   cg[k] = t[k]*rb[k]*sigmoid(t[k]*rb[k]*w[0][k])
// Phase 2: out[e][lm][k] = Y[lm] * cg[k] * w[deg(lm)][k].  For each phase-2
// thread, j = tid&31 is iteration-invariant => (lm, k0, deg) fixed => its
// w[deg][k0..3] float4 lives in registers, loaded once.
// LDS = 25.6 KB/block -> 6 blocks/CU -> 24 waves/CU.
// ---------------------------------------------------------------------------
__global__ __launch_bounds__(256) void srb_main(
    const float* __restrict__ disp,
    const int*   __restrict__ Zj,
    const float* __restrict__ tw,       // tensor_w, 4 x 8
    const float* __restrict__ t_table,  // 83 x 8
    float*       __restrict__ out,
    int n_edges)
{
    __shared__ float Yl[TILE * 17];    // stride 17 (odd): conflict-free b32
    __shared__ float CGl[TILE * 8];    // stride 8: 2-way aliasing (free)

    const int tid = threadIdx.x;
    const int e   = blockIdx.x * TILE + tid;

    // ---- phase-2 invariants (depend only on tid&31) ----
    const int jj  = tid & 31;          // float4-slot within an edge
    const int lm  = jj >> 1;           // 0..15
    const int k0  = (jj & 1) * 4;      // 0 or 4
    const int l   = (lm > 0) + (lm > 3) + (lm > 8);
    const f4  wl  = *reinterpret_cast<const f4*>(tw + l * NUM_RADIAL + k0);

    if (e < n_edges) {
        const float dx = disp[3 * e + 0];
        const float dy = disp[3 * e + 1];
        const float dz = disp[3 * e + 2];
        const float r2 = dx * dx + dy * dy + dz * dz;
        const float r  = sqrtf(r2);
        const float rinv = (r > 0.0f) ? __builtin_amdgcn_rcpf(r) : 0.0f;
        const float x = dx * rinv, y = dy * rinv, z = dz * rinv;
        const float x2 = x * x, y2 = y * y, z2 = z * z;

        const float s3   = 1.7320508075688772f;   // sqrt(3)
        const float s15  = 3.8729833462074170f;   // sqrt(15)
        const float s5_8 = 0.7905694150420949f;   // sqrt(5/8)
        const float s3_8 = 0.6123724356957945f;   // sqrt(3/8)

        float* Yp = &Yl[tid * 17];
        Yp[0]  = 1.0f;
        Yp[1]  = x;
        Yp[2]  = y;
        Yp[3]  = z;
        Yp[4]  = s3 * x * y;
        Yp[5]  = s3 * y * z;
        Yp[6]  = 0.5f * (3.0f * z2 - 1.0f);
        Yp[7]  = s3 * x * z;
        Yp[8]  = 0.5f * s3 * (x2 - y2);
        Yp[9]  = s5_8 * y * (3.0f * x2 - y2);
        Yp[10] = s15 * x * y * z;
        Yp[11] = s3_8 * y * (5.0f * z2 - 1.0f);
        Yp[12] = 0.5f * z * (5.0f * z2 - 3.0f);
        Yp[13] = s3_8 * x * (5.0f * z2 - 1.0f);
        Yp[14] = 0.5f * s15 * z * (x2 - y2);
        Yp[15] = s5_8 * x * (x2 - 3.0f * y2);

        const float PI  = 3.14159265358979323846f;
        const float cut = (r < 5.0f) ? (0.5f * (__cosf(PI * r * 0.2f) + 1.0f))
                                     : 0.0f;
        const float pib = PI * r * 0.2f;   // pi*r/CUTOFF

        const int zidx = Zj[e];
        const f4 t0 = *reinterpret_cast<const f4*>(t_table + zidx * NUM_RADIAL);
        const f4 t1 = *reinterpret_cast<const f4*>(t_table + zidx * NUM_RADIAL + 4);
        float t[NUM_RADIAL] = { t0.x, t0.y, t0.z, t0.w, t1.x, t1.y, t1.z, t1.w };

        f4 cga, cgb;
        #pragma unroll
        for (int k = 0; k < NUM_RADIAL; ++k) {
            const float px = pib * (float)(k + 1);
            const float s  = (px != 0.0f) ? (__sinf(px) * __builtin_amdgcn_rcpf(px))
                                          : 1.0f;              // sinc
            const float c  = t[k] * (s * cut);
            const float y0 = c * tw[k];                         // w[0][k]
            const float gate = __builtin_amdgcn_rcpf(1.0f + __expf(-y0));
            const float cg = c * gate;
            if (k < 4) ((float*)&cga)[k] = cg; else ((float*)&cgb)[k - 4] = cg;
        }
        f4* CGp = reinterpret_cast<f4*>(&CGl[tid * 8]);
        CGp[0] = cga;
        CGp[1] = cgb;
    }

    __syncthreads();

    // Phase 2: coalesced output stream, 32 float4 per edge
    const int totalF4 = n_edges * 32;
    const int baseF4  = blockIdx.x * (TILE * 32);
    f4* out4 = reinterpret_cast<f4*>(out);
    #pragma unroll
    for (int it = 0; it < 32; ++it) {
        const int lf = it * 256 + tid;                 // [0, 8192)
        const int f  = baseF4 + lf;
        if (f < totalF4) {
            const int el = lf >> 5;                    // local edge 0..255
            const float yv = Yl[el * 17 + lm];
            const f4 cg = *reinterpret_cast<const f4*>(&CGl[el * 8 + k0]);
            const f4 o  = (yv * cg) * wl;
            out4[f] = o;
        }
    }
}

extern "C" void kernel_launch(void* const* d_in, const int* in_sizes, int n_in,
                              void* d_out, int out_size, void* d_ws, size_t ws_size,
                              hipStream_t stream) {
    const float* disp = (const float*)d_in[0];
    const int*   Zj   = (const int*)  d_in[1];
    const float* emb  = (const float*)d_in[2];
    const float* dw   = (const float*)d_in[3];
    const float* db   = (const float*)d_in[4];
    const float* tw   = (const float*)d_in[5];
    float* t_table = (float*)d_ws;                    // 83*8 floats = 2656 B
    float* out     = (float*)d_out;

    const int n = in_sizes[1];                        // N_EDGES

    hipLaunchKernelGGL(srb_precompute_t, dim3(3), dim3(256), 0, stream,
                       emb, dw, db, t_table);

    const int nblocks = (n + TILE - 1) / TILE;
    hipLaunchKernelGGL(srb_main, dim3(nblocks), dim3(256), 0, stream,
                       disp, Zj, tw, t_table, out, n);
}

// Round 5
// 42.098 us; speedup vs baseline: 1.1534x; 1.0692x over previous
//
#include <hip/hip_runtime.h>
#include <math.h>

#define NUM_RADIAL 8
#define EMB_DIM    64
#define N_ELEM     83
#define TILE       256   // edges per block; each wave owns 64 edges

typedef float f4 __attribute__((ext_vector_type(4)));

// ---------------------------------------------------------------------------
// Kernel 1: t_table[z][k] = emb_table[z] . dense_w[:,k] + dense_b[k]
// ---------------------------------------------------------------------------
__global__ void srb_precompute_t(const float* __restrict__ emb,
                                 const float* __restrict__ dw,
                                 const float* __restrict__ db,
                                 float* __restrict__ t_table) {
    int idx = blockIdx.x * blockDim.x + threadIdx.x;
    if (idx >= N_ELEM * NUM_RADIAL) return;
    int z = idx >> 3;
    int k = idx & 7;
    float acc = db[k];
    const float* e = emb + z * EMB_DIM;
    #pragma unroll 8
    for (int j = 0; j < EMB_DIM; ++j)
        acc += e[j] * dw[j * NUM_RADIAL + k];
    t_table[idx] = acc;
}

// ---------------------------------------------------------------------------
// Kernel 2: main edge kernel — wave-synchronous, NO __syncthreads.
// Each wave owns a 64-edge segment. Phase 1: lane i computes edge i's Y[16]
// (LDS stride 17) and gated radial cg[8] (LDS stride 12, 48B rows). Phase 2:
// after a wave-local s_waitcnt lgkmcnt(0), the same wave re-maps lanes so one
// wave-instruction stores 1KB contiguous (2 edges x 512B) per iteration.
// out[e][lm][k] = Y[lm] * cg[k] * w[deg(lm)][k]; each thread's (lm,k0,deg)
// is fixed => its w[deg][k0..3] float4 stays in registers.
// Waves never wait on each other -> independent store streams.
// ---------------------------------------------------------------------------
__global__ __launch_bounds__(256) void srb_main(
    const float* __restrict__ disp,
    const int*   __restrict__ Zj,
    const float* __restrict__ tw,       // tensor_w, 4 x 8
    const float* __restrict__ t_table,  // 83 x 8
    float*       __restrict__ out,
    int n_edges)
{
    __shared__ float Yl[TILE * 17];    // stride 17 (odd): conflict-free b32
    __shared__ float CGl[TILE * 12];   // stride 12 floats = 48B, 16B-aligned

    const int tid  = threadIdx.x;
    const int lane = tid & 63;
    const int wv   = tid >> 6;
    const int e    = blockIdx.x * TILE + tid;

    // ---- phase-2 invariants (depend only on lane&31) ----
    const int jj  = lane & 31;         // float4-slot within an edge
    const int lm  = jj >> 1;           // 0..15
    const int k0  = (jj & 1) * 4;      // 0 or 4
    const int l   = (lm > 0) + (lm > 3) + (lm > 8);
    const f4  wl  = *reinterpret_cast<const f4*>(tw + l * NUM_RADIAL + k0);

    if (e < n_edges) {
        const float dx = disp[3 * e + 0];
        const float dy = disp[3 * e + 1];
        const float dz = disp[3 * e + 2];
        const float r2 = dx * dx + dy * dy + dz * dz;
        const float r  = sqrtf(r2);
        const float rinv = (r > 0.0f) ? __builtin_amdgcn_rcpf(r) : 0.0f;
        const float x = dx * rinv, y = dy * rinv, z = dz * rinv;
        const float x2 = x * x, y2 = y * y, z2 = z * z;

        const float s3   = 1.7320508075688772f;   // sqrt(3)
        const float s15  = 3.8729833462074170f;   // sqrt(15)
        const float s5_8 = 0.7905694150420949f;   // sqrt(5/8)
        const float s3_8 = 0.6123724356957945f;   // sqrt(3/8)

        float* Yp = &Yl[tid * 17];
        Yp[0]  = 1.0f;
        Yp[1]  = x;
        Yp[2]  = y;
        Yp[3]  = z;
        Yp[4]  = s3 * x * y;
        Yp[5]  = s3 * y * z;
        Yp[6]  = 0.5f * (3.0f * z2 - 1.0f);
        Yp[7]  = s3 * x * z;
        Yp[8]  = 0.5f * s3 * (x2 - y2);
        Yp[9]  = s5_8 * y * (3.0f * x2 - y2);
        Yp[10] = s15 * x * y * z;
        Yp[11] = s3_8 * y * (5.0f * z2 - 1.0f);
        Yp[12] = 0.5f * z * (5.0f * z2 - 3.0f);
        Yp[13] = s3_8 * x * (5.0f * z2 - 1.0f);
        Yp[14] = 0.5f * s15 * z * (x2 - y2);
        Yp[15] = s5_8 * x * (x2 - 3.0f * y2);

        const float PI  = 3.14159265358979323846f;
        const float cut = (r < 5.0f) ? (0.5f * (__cosf(PI * r * 0.2f) + 1.0f))
                                     : 0.0f;
        const float pib = PI * r * 0.2f;   // pi*r/CUTOFF

        const int zidx = Zj[e];
        const f4 t0 = *reinterpret_cast<const f4*>(t_table + zidx * NUM_RADIAL);
        const f4 t1 = *reinterpret_cast<const f4*>(t_table + zidx * NUM_RADIAL + 4);
        float t[NUM_RADIAL] = { t0.x, t0.y, t0.z, t0.w, t1.x, t1.y, t1.z, t1.w };

        f4 cga, cgb;
        #pragma unroll
        for (int k = 0; k < NUM_RADIAL; ++k) {
            const float px = pib * (float)(k + 1);
            const float s  = (px != 0.0f) ? (__sinf(px) * __builtin_amdgcn_rcpf(px))
                                          : 1.0f;              // sinc
            const float c  = t[k] * (s * cut);
            const float y0 = c * tw[k];                         // w[0][k]
            const float gate = __builtin_amdgcn_rcpf(1.0f + __expf(-y0));
            const float cg = c * gate;
            if (k < 4) ((float*)&cga)[k] = cg; else ((float*)&cgb)[k - 4] = cg;
        }
        f4* CGp = reinterpret_cast<f4*>(&CGl[tid * 12]);
        CGp[0] = cga;
        CGp[1] = cgb;
    }

    // Wave-local phase boundary: drain this wave's LDS writes, pin ordering.
    __asm__ volatile("s_waitcnt lgkmcnt(0)" ::: "memory");
    __builtin_amdgcn_sched_barrier(0);

    // Phase 2: this wave streams its own 64 edges (2 edges / wave-inst,
    // 1KB contiguous per wave-instruction).
    const int el0 = wv * 64;
    f4* out4 = reinterpret_cast<f4*>(out);
    #pragma unroll 8
    for (int it = 0; it < 32; ++it) {
        const int el   = el0 + it * 2 + (lane >> 5);   // local edge
        const int edge = blockIdx.x * TILE + el;
        if (edge < n_edges) {
            const float yv = Yl[el * 17 + lm];
            const f4 cg = *reinterpret_cast<const f4*>(&CGl[el * 12 + k0]);
            const f4 o  = (yv * cg) * wl;
            out4[edge * 32 + jj] = o;
        }
    }
}

extern "C" void kernel_launch(void* const* d_in, const int* in_sizes, int n_in,
                              void* d_out, int out_size, void* d_ws, size_t ws_size,
                              hipStream_t stream) {
    const float* disp = (const float*)d_in[0];
    const int*   Zj   = (const int*)  d_in[1];
    const float* emb  = (const float*)d_in[2];
    const float* dw   = (const float*)d_in[3];
    const float* db   = (const float*)d_in[4];
    const float* tw   = (const float*)d_in[5];
    float* t_table = (float*)d_ws;                    // 83*8 floats = 2656 B
    float* out     = (float*)d_out;

    const int n = in_sizes[1];                        // N_EDGES

    hipLaunchKernelGGL(srb_precompute_t, dim3(3), dim3(256), 0, stream,
                       emb, dw, db, t_table);

    const int nblocks = (n + TILE - 1) / TILE;
    hipLaunchKernelGGL(srb_main, dim3(nblocks), dim3(256), 0, stream,
                       disp, Zj, tw, t_table, out, n);
}